// Round 4
// baseline (1214.339 us; speedup 1.0000x reference)
//
#include <hip/hip_runtime.h>
#include <stdint.h>
#include <stddef.h>

typedef __attribute__((ext_vector_type(4))) float floatx4;
typedef __attribute__((ext_vector_type(8))) short shortx8;
typedef __attribute__((ext_vector_type(4))) short shortx4;
typedef __attribute__((ext_vector_type(4))) _Float16 halfx4;

#define DEVI static __device__ __forceinline__

DEVI uint16_t f2bf(float f) {
  uint32_t u = __builtin_bit_cast(uint32_t, f);
  u += 0x7fffu + ((u >> 16) & 1u);
  return (uint16_t)(u >> 16);
}
DEVI float bf2f(uint16_t u) {
  return __builtin_bit_cast(float, (uint32_t)u << 16);
}

// async global->LDS, 16 bytes per lane
DEVI void gload_lds16(const void* g, void* lds) {
  unsigned int off = (unsigned int)(uintptr_t)lds;
  __builtin_amdgcn_global_load_lds(
      (const __attribute__((address_space(1))) unsigned int*)g,
      (__attribute__((address_space(3))) unsigned int*)off,
      16, 0, 0);
}

// ---------------- prep kernels ----------------

// inp [384][512][64] fp32 -> Xb [384*64][512] bf16, LDS-transposed for coalescing.
__global__ __launch_bounds__(256) void k_prep_x(const float* __restrict__ inp,
                                                uint16_t* __restrict__ Xb) {
  __shared__ float T[64 * 65];
  const int tid = threadIdx.x;
  const int t = blockIdx.x >> 3, cb = blockIdx.x & 7;
  const float* src = inp + ((size_t)t * 512 + cb * 64) * 64;
  {
    int ci = tid >> 2, so = (tid & 3) * 16;
#pragma unroll
    for (int j = 0; j < 4; ++j) {
      float4 v = *(const float4*)&src[ci * 64 + so + 4 * j];
      T[ci * 65 + so + 4 * j + 0] = v.x;
      T[ci * 65 + so + 4 * j + 1] = v.y;
      T[ci * 65 + so + 4 * j + 2] = v.z;
      T[ci * 65 + so + 4 * j + 3] = v.w;
    }
  }
  __syncthreads();
  {
    int s = tid >> 2, co = (tid & 3) * 16;
    uint16_t* dst = Xb + ((size_t)(t * 64 + s) * 512) + cb * 64 + co;
    shortx8 o0, o1;
#pragma unroll
    for (int j = 0; j < 8; ++j) o0[j] = (short)f2bf(T[(co + j) * 65 + s]);
#pragma unroll
    for (int j = 0; j < 8; ++j) o1[j] = (short)f2bf(T[(co + 8 + j) * 65 + s]);
    *(shortx8*)dst = o0;
    *(shortx8*)(dst + 8) = o1;
  }
}

// w_in [2560][512][3][3] fp32 -> Wr [9][2560][512] bf16 with co' = e*512+h*64+d
__global__ __launch_bounds__(256) void k_prep_win(const float* __restrict__ w_in,
                                                  const float* __restrict__ b_in,
                                                  uint16_t* __restrict__ Wr,
                                                  float* __restrict__ bias_p) {
  __shared__ float B[4608];
  const int tid = threadIdx.x;
  const int cp = blockIdx.x;
  const int e = cp >> 9, h = (cp >> 6) & 7, d = cp & 63;
  const int co = e * 512 + d * 8 + h;
  const float* src = w_in + (size_t)co * 4608;
#pragma unroll
  for (int it = 0; it < 9; ++it) {
    int i2 = it * 256 + tid;
    *(float2*)&B[i2 * 2] = *(const float2*)&src[i2 * 2];
  }
  if (tid == 0) bias_p[cp] = b_in[co];
  __syncthreads();
  const int ci = tid * 2;
#pragma unroll
  for (int tap = 0; tap < 9; ++tap) {
    uint32_t pk = (uint32_t)f2bf(B[ci * 9 + tap]) |
                  ((uint32_t)f2bf(B[(ci + 1) * 9 + tap]) << 16);
    *(uint32_t*)&Wr[((size_t)tap * 2560 + cp) * 512 + ci] = pk;
  }
}

// w_out [512][512][3][3] fp32 -> Wr [9][512][512] bf16, in-channel perm c2'=h*64+d
__global__ __launch_bounds__(256) void k_prep_wout(const float* __restrict__ w_out,
                                                   uint16_t* __restrict__ Wr) {
  __shared__ float B[4608];
  const int tid = threadIdx.x;
  const int co2 = blockIdx.x;
  const float* src = w_out + (size_t)co2 * 4608;
#pragma unroll
  for (int it = 0; it < 9; ++it) {
    int i2 = it * 256 + tid;
    *(float2*)&B[i2 * 2] = *(const float2*)&src[i2 * 2];
  }
  __syncthreads();
  const int c2 = tid * 2;
  const int oci0 = (c2 & 63) * 8 + (c2 >> 6);
  const int oci1 = ((c2 + 1) & 63) * 8 + ((c2 + 1) >> 6);
#pragma unroll
  for (int tap = 0; tap < 9; ++tap) {
    uint32_t pk = (uint32_t)f2bf(B[oci0 * 9 + tap]) |
                  ((uint32_t)f2bf(B[oci1 * 9 + tap]) << 16);
    *(uint32_t*)&Wr[((size_t)tap * 512 + co2) * 512 + c2] = pk;
  }
}

// masks -> transposed [h][k][q]; amT pre-scaled by log2(e)
__global__ __launch_bounds__(256) void k_prep_mask(const float* __restrict__ am,
                                                   const int* __restrict__ gm,
                                                   float* __restrict__ amT,
                                                   float* __restrict__ gmT) {
  __shared__ float A_[64 * 65];
  __shared__ float G_[64 * 65];
  const int tid = threadIdx.x;
  const int b = blockIdx.x;
  const int h = b / 36, rr = b % 36;
  const int q0 = (rr / 6) * 64, k0 = (rr % 6) * 64;
  {
    int qr = tid >> 2, ko = (tid & 3) * 16;
    const float* ap = am + ((size_t)h * 384 + q0 + qr) * 384 + k0 + ko;
    const int* gp = gm + ((size_t)h * 384 + q0 + qr) * 384 + k0 + ko;
#pragma unroll
    for (int j = 0; j < 4; ++j) {
      float4 v = *(const float4*)(ap + 4 * j);
      int4 g = *(const int4*)(gp + 4 * j);
      int kk = ko + 4 * j;
      A_[(kk + 0) * 65 + qr] = v.x;
      A_[(kk + 1) * 65 + qr] = v.y;
      A_[(kk + 2) * 65 + qr] = v.z;
      A_[(kk + 3) * 65 + qr] = v.w;
      G_[(kk + 0) * 65 + qr] = (float)g.x;
      G_[(kk + 1) * 65 + qr] = (float)g.y;
      G_[(kk + 2) * 65 + qr] = (float)g.z;
      G_[(kk + 3) * 65 + qr] = (float)g.w;
    }
  }
  __syncthreads();
  {
    const float L2E = 1.44269504f;
    int kr = tid >> 2, qo = (tid & 3) * 16;
    float* aop = amT + ((size_t)h * 384 + k0 + kr) * 384 + q0 + qo;
    float* gop = gmT + ((size_t)h * 384 + k0 + kr) * 384 + q0 + qo;
#pragma unroll
    for (int j = 0; j < 4; ++j) {
      float4 o, g;
      o.x = A_[kr * 65 + qo + 4 * j + 0] * L2E;
      o.y = A_[kr * 65 + qo + 4 * j + 1] * L2E;
      o.z = A_[kr * 65 + qo + 4 * j + 2] * L2E;
      o.w = A_[kr * 65 + qo + 4 * j + 3] * L2E;
      g.x = G_[kr * 65 + qo + 4 * j + 0];
      g.y = G_[kr * 65 + qo + 4 * j + 1];
      g.z = G_[kr * 65 + qo + 4 * j + 2];
      g.w = G_[kr * 65 + qo + 4 * j + 3];
      *(float4*)(aop + 4 * j) = o;
      *(float4*)(gop + 4 * j) = g;
    }
  }
}

// ---------------- implicit-GEMM 3x3 conv (pad 1) ----------------
// 512 threads, 8 waves in 4(m) x 2(n) grid; per-wave acc 2x4 16x16 tiles
// (32 AGPRs) so VGPR+AGPR fits 128 -> 4 waves/SIMD occupancy.
template <int MTOT, int EPI>
__global__ __launch_bounds__(512, 4) void conv_gemm(const uint16_t* __restrict__ W,
                                                    const uint16_t* __restrict__ X,
                                                    const float* __restrict__ bias,
                                                    uint16_t* __restrict__ Fo,
                                                    float* __restrict__ Oo,
                                                    int m_off) {
  __shared__ __attribute__((aligned(16))) uint16_t Wl[128 * 64];
  __shared__ __attribute__((aligned(16))) uint16_t Xl[128 * 64];

  const int tid = threadIdx.x;
  const int lane = tid & 63;
  const int wave = tid >> 6;
  const int quad = lane >> 4;
  const int l15 = lane & 15;
  const int wm = wave >> 1;  // 0..3 : 32 m-rows each
  const int wn = wave & 1;   // 0..1 : 64 n-cols each

  const int m_blk = blockIdx.x / 192;
  const int n_blk = blockIdx.x % 192;
  const int m0 = m_off + m_blk * 128;
  const long n0 = (long)n_blk * 128;

  const int srow0 = tid >> 3;  // 0..63 (+64 second round)
  const int spos = tid & 7;

  floatx4 acc[2][4];
#pragma unroll
  for (int i = 0; i < 2; ++i)
#pragma unroll
    for (int j = 0; j < 4; ++j) acc[i][j] = (floatx4)0.0f;

  int arow[2];
#pragma unroll
  for (int mt = 0; mt < 2; ++mt) arow[mt] = wm * 32 + mt * 16 + l15;

  for (int kc = 0; kc < 8; ++kc) {
    for (int tap = 0; tap < 9; ++tap) {
      __syncthreads();
      if (tap == 0) {
#pragma unroll
        for (int i = 0; i < 2; ++i) {
          int row = srow0 + i * 64;
          int c = spos ^ (row & 7);
          gload_lds16(X + ((n0 + row) * 512 + kc * 64 + c * 8),
                      Xl + row * 64 + spos * 8);
        }
      }
      {
        const uint16_t* wg = W + ((size_t)tap * MTOT + m0) * 512 + kc * 64;
#pragma unroll
        for (int i = 0; i < 2; ++i) {
          int row = srow0 + i * 64;
          int c = spos ^ (row & 7);
          gload_lds16(wg + (size_t)row * 512 + c * 8, Wl + row * 64 + spos * 8);
        }
      }
      __syncthreads();

      const int dy = tap / 3 - 1, dx = tap % 3 - 1;
      int brow[4];
      bool bok[4];
#pragma unroll
      for (int nt = 0; nt < 4; ++nt) {
        int s = nt * 16 + l15;
        int y = (s >> 3) + dy, x = (s & 7) + dx;
        bool ok = ((unsigned)y < 8u) && ((unsigned)x < 8u);
        bok[nt] = ok;
        brow[nt] = wn * 64 + (ok ? (y * 8 + x) : 0);
      }

#pragma unroll
      for (int ks = 0; ks < 2; ++ks) {
        shortx8 af[2], bf[4];
#pragma unroll
        for (int mt = 0; mt < 2; ++mt) {
          int pos = ((ks << 2) | quad) ^ (arow[mt] & 7);
          af[mt] = *(const shortx8*)(Wl + arow[mt] * 64 + pos * 8);
        }
#pragma unroll
        for (int nt = 0; nt < 4; ++nt) {
          int pos = ((ks << 2) | quad) ^ (brow[nt] & 7);
          shortx8 v = *(const shortx8*)(Xl + brow[nt] * 64 + pos * 8);
          bf[nt] = bok[nt] ? v : (shortx8)(short)0;
        }
#pragma unroll
        for (int mt = 0; mt < 2; ++mt)
#pragma unroll
          for (int nt = 0; nt < 4; ++nt)
            acc[mt][nt] = __builtin_amdgcn_mfma_f32_16x16x32_bf16(
                af[mt], bf[nt], acc[mt][nt], 0, 0, 0);
      }
    }
  }

  if (EPI == 0) {
#pragma unroll
    for (int mt = 0; mt < 2; ++mt) {
      int cpb = m0 + wm * 32 + mt * 16 + quad * 4;
      floatx4 bv = *(const floatx4*)(bias + cpb);
      int e = cpb >> 9, h = (cpb >> 6) & 7, d0 = cpb & 63;
#pragma unroll
      for (int nt = 0; nt < 4; ++nt) {
        long ng = n0 + wn * 64 + nt * 16 + l15;
        int t = (int)(ng >> 6), p = (int)(ng & 63);
        shortx4 pk;
#pragma unroll
        for (int r = 0; r < 4; ++r) pk[r] = (short)f2bf(acc[mt][nt][r] + bv[r]);
        *(shortx4*)(Fo + ((((size_t)(e * 8 + h) * 64 + p) * 384 + t) * 64 + d0)) = pk;
      }
    }
  } else {
#pragma unroll
    for (int mt = 0; mt < 2; ++mt) {
      int co = m0 + wm * 32 + mt * 16 + quad * 4;
      floatx4 bv = *(const floatx4*)(bias + co);
#pragma unroll
      for (int nt = 0; nt < 4; ++nt) {
        long ng = n0 + wn * 64 + nt * 16 + l15;
        int t = (int)(ng >> 6), s = (int)(ng & 63);
        float* op = Oo + ((size_t)t * 512 + co) * 64 + s;
#pragma unroll
        for (int r = 0; r < 4; ++r) op[(size_t)r * 64] = acc[mt][nt][r] + bv[r];
      }
    }
  }
}

// ---------------- agent-aware attention, transpose-free ----------------
__global__ __launch_bounds__(256) void attn_kernel(const uint16_t* __restrict__ F,
                                                   const float* __restrict__ amT,
                                                   const float* __restrict__ gmT,
                                                   uint16_t* __restrict__ G) {
  __shared__ __attribute__((aligned(16))) _Float16 Vt[64 * 392];  // [d][kk]

  const int tid = threadIdx.x;
  const int lane = tid & 63;
  const int wave = tid >> 6;
  const int quad = lane >> 4;
  const int l15 = lane & 15;

  const int qt = blockIdx.x % 6;
  const int hp = blockIdx.x / 6;
  const int h = hp >> 6, p = hp & 63;

  const size_t slab = (size_t)384 * 64;
  const uint16_t* Ks = F + ((size_t)(0 * 8 + h) * 64 + p) * slab;
  const uint16_t* Ko = F + ((size_t)(1 * 8 + h) * 64 + p) * slab;
  const uint16_t* Qs = F + ((size_t)(2 * 8 + h) * 64 + p) * slab;
  const uint16_t* Qo = F + ((size_t)(3 * 8 + h) * 64 + p) * slab;
  const uint16_t* Vv = F + ((size_t)(4 * 8 + h) * 64 + p) * slab;

  if (tid < 192) {
    const int kk0 = tid * 2;
    const uint16_t* v0 = Vv + (size_t)kk0 * 64;
#pragma unroll
    for (int dc = 0; dc < 8; ++dc) {
      shortx8 a = *(const shortx8*)(v0 + dc * 8);
      shortx8 b = *(const shortx8*)(v0 + 64 + dc * 8);
#pragma unroll
      for (int e = 0; e < 8; ++e) {
        _Float16 fa = (_Float16)bf2f((uint16_t)a[e]);
        _Float16 fb = (_Float16)bf2f((uint16_t)b[e]);
        uint32_t pk = (uint32_t)__builtin_bit_cast(uint16_t, fa) |
                      ((uint32_t)__builtin_bit_cast(uint16_t, fb) << 16);
        *(uint32_t*)&Vt[(dc * 8 + e) * 392 + kk0] = pk;
      }
    }
  }

  const int q0 = qt * 64 + wave * 16;
  shortx8 qsf[2], qof[2];
#pragma unroll
  for (int ks = 0; ks < 2; ++ks) {
    qsf[ks] = *(const shortx8*)(Qs + (size_t)(q0 + l15) * 64 + ks * 32 + quad * 8);
    qof[ks] = *(const shortx8*)(Qo + (size_t)(q0 + l15) * 64 + ks * 32 + quad * 8);
  }

  floatx4 Os[4], Oo[4];
#pragma unroll
  for (int i = 0; i < 4; ++i) { Os[i] = (floatx4)0.0f; Oo[i] = (floatx4)0.0f; }
  float ms = -1e30f, mo = -1e30f, ls = 0.f, lo = 0.f;

  const float C1 = 0.125f * 1.44269504f;

  __syncthreads();

  for (int kb = 0; kb < 6; ++kb) {
    const int k0 = kb * 64;

    const float* amr = amT + ((size_t)h * 384 + k0 + quad * 4) * 384 + q0 + l15;
    float am[4][4];
#pragma unroll
    for (int nt = 0; nt < 4; ++nt)
#pragma unroll
      for (int r = 0; r < 4; ++r) am[nt][r] = amr[((size_t)nt * 16 + r) * 384];

    floatx4 Ss[4], So[4];
#pragma unroll
    for (int nt = 0; nt < 4; ++nt) { Ss[nt] = (floatx4)0.0f; So[nt] = (floatx4)0.0f; }
#pragma unroll
    for (int nt = 0; nt < 4; ++nt) {
      const size_t krow = (size_t)(k0 + nt * 16 + l15) * 64;
#pragma unroll
      for (int ks = 0; ks < 2; ++ks) {
        shortx8 ka = *(const shortx8*)(Ks + krow + ks * 32 + quad * 8);
        Ss[nt] = __builtin_amdgcn_mfma_f32_16x16x32_bf16(ka, qsf[ks], Ss[nt], 0, 0, 0);
        shortx8 kb_ = *(const shortx8*)(Ko + krow + ks * 32 + quad * 8);
        So[nt] = __builtin_amdgcn_mfma_f32_16x16x32_bf16(kb_, qof[ks], So[nt], 0, 0, 0);
      }
    }

    float Ps[4][4], Po[4][4];
#pragma unroll
    for (int nt = 0; nt < 4; ++nt)
#pragma unroll
      for (int r = 0; r < 4; ++r) {
        Ps[nt][r] = Ss[nt][r] * C1 + am[nt][r];
        Po[nt][r] = So[nt][r] * C1 + am[nt][r];
      }

    {
      float mx = Ps[0][0];
#pragma unroll
      for (int nt = 0; nt < 4; ++nt)
#pragma unroll
        for (int r = 0; r < 4; ++r) mx = fmaxf(mx, Ps[nt][r]);
      mx = fmaxf(mx, __shfl_xor(mx, 16));
      mx = fmaxf(mx, __shfl_xor(mx, 32));
      float nm = fmaxf(ms, mx);
      float al = exp2f(ms - nm);
      ms = nm;
      float rs = 0.f;
#pragma unroll
      for (int nt = 0; nt < 4; ++nt)
#pragma unroll
        for (int r = 0; r < 4; ++r) {
          float pe = exp2f(Ps[nt][r] - nm);
          Ps[nt][r] = pe;
          rs += pe;
        }
      rs += __shfl_xor(rs, 16);
      rs += __shfl_xor(rs, 32);
      ls = ls * al + rs;
#pragma unroll
      for (int dt = 0; dt < 4; ++dt) Os[dt] = Os[dt] * al;
    }
    {
      float mx = Po[0][0];
#pragma unroll
      for (int nt = 0; nt < 4; ++nt)
#pragma unroll
        for (int r = 0; r < 4; ++r) mx = fmaxf(mx, Po[nt][r]);
      mx = fmaxf(mx, __shfl_xor(mx, 16));
      mx = fmaxf(mx, __shfl_xor(mx, 32));
      float nm = fmaxf(mo, mx);
      float al = exp2f(mo - nm);
      mo = nm;
      float rs = 0.f;
#pragma unroll
      for (int nt = 0; nt < 4; ++nt)
#pragma unroll
        for (int r = 0; r < 4; ++r) {
          float pe = exp2f(Po[nt][r] - nm);
          Po[nt][r] = pe;
          rs += pe;
        }
      rs += __shfl_xor(rs, 16);
      rs += __shfl_xor(rs, 32);
      lo = lo * al + rs;
#pragma unroll
      for (int dt = 0; dt < 4; ++dt) Oo[dt] = Oo[dt] * al;
    }

    const float* gmr = gmT + ((size_t)h * 384 + k0 + quad * 4) * 384 + q0 + l15;
    halfx4 pbs[4], pbo[4];
#pragma unroll
    for (int kt = 0; kt < 4; ++kt)
#pragma unroll
      for (int r = 0; r < 4; ++r) {
        float g = gmr[((size_t)kt * 16 + r) * 384];
        pbs[kt][r] = (_Float16)(Ps[kt][r] * g);
        pbo[kt][r] = (_Float16)(Po[kt][r] * (1.f - g));
      }

#pragma unroll
    for (int dt = 0; dt < 4; ++dt) {
      const _Float16* vrow = Vt + (size_t)(dt * 16 + l15) * 392 + k0;
#pragma unroll
      for (int kt = 0; kt < 4; ++kt) {
        halfx4 va = *(const halfx4*)(vrow + kt * 16 + quad * 4);
        Os[dt] = __builtin_amdgcn_mfma_f32_16x16x16f16(va, pbs[kt], Os[dt], 0, 0, 0);
        Oo[dt] = __builtin_amdgcn_mfma_f32_16x16x16f16(va, pbo[kt], Oo[dt], 0, 0, 0);
      }
    }
  }

  const float is = 1.f / ls, io = 1.f / lo;
  const int q = q0 + l15;
#pragma unroll
  for (int dt = 0; dt < 4; ++dt) {
    shortx4 pk;
#pragma unroll
    for (int r = 0; r < 4; ++r) pk[r] = (short)f2bf(Os[dt][r] * is + Oo[dt][r] * io);
    *(shortx4*)(G + ((size_t)q * 64 + p) * 512 + h * 64 + dt * 16 + quad * 4) = pk;
  }
}

// ---------------- launch ----------------

extern "C" void kernel_launch(void* const* d_in, const int* in_sizes, int n_in,
                              void* d_out, int out_size, void* d_ws, size_t ws_size,
                              hipStream_t stream) {
  (void)in_sizes; (void)n_in; (void)out_size;

  const float* inp   = (const float*)d_in[0];
  const float* amask = (const float*)d_in[1];
  const int*   gmask = (const int*)d_in[2];
  const float* w_in  = (const float*)d_in[3];
  const float* b_in  = (const float*)d_in[4];
  const float* w_out = (const float*)d_in[5];
  const float* b_out = (const float*)d_in[6];
  float* out = (float*)d_out;

  const size_t SZ_WRIN  = (size_t)9 * 2560 * 512 * 2;
  const size_t SZ_WROUT = (size_t)9 * 512 * 512 * 2;
  const size_t SZ_BIAS  = 2560 * 4;
  const size_t SZ_XB    = (size_t)24576 * 512 * 2;
  const size_t SZ_F     = (size_t)5 * 8 * 64 * 384 * 64 * 2;
  if (ws_size < SZ_WRIN + SZ_WROUT + SZ_BIAS + SZ_XB + SZ_F) return;

  char* ws = (char*)d_ws;
  uint16_t* Wr_in  = (uint16_t*)ws;  ws += SZ_WRIN;
  uint16_t* Wr_out = (uint16_t*)ws;  ws += SZ_WROUT;
  float*    bias_p = (float*)ws;     ws += SZ_BIAS;
  uint16_t* Xb     = (uint16_t*)ws;  ws += SZ_XB;
  uint16_t* F      = (uint16_t*)ws;  ws += SZ_F;
  uint16_t* G      = Xb;             // Xb dead after conv_in
  float*    amT    = (float*)Wr_in;  // Wr_in dead after conv_in
  float*    gmT    = amT + (size_t)8 * 384 * 384;

  k_prep_x<<<3072, 256, 0, stream>>>(inp, Xb);
  k_prep_win<<<2560, 256, 0, stream>>>(w_in, b_in, Wr_in, bias_p);
  k_prep_wout<<<512, 256, 0, stream>>>(w_out, Wr_out);
  // conv_in split into 4 dispatches (5 m-blocks each) for rocprof top-k visibility
  conv_gemm<2560, 0><<<5 * 192, 512, 0, stream>>>(Wr_in, Xb, bias_p, F, nullptr, 0);
  conv_gemm<2560, 0><<<5 * 192, 512, 0, stream>>>(Wr_in, Xb, bias_p, F, nullptr, 640);
  conv_gemm<2560, 0><<<5 * 192, 512, 0, stream>>>(Wr_in, Xb, bias_p, F, nullptr, 1280);
  conv_gemm<2560, 0><<<5 * 192, 512, 0, stream>>>(Wr_in, Xb, bias_p, F, nullptr, 1920);
  k_prep_mask<<<288, 256, 0, stream>>>(amask, gmask, amT, gmT);
  attn_kernel<<<512 * 6, 256, 0, stream>>>(F, amT, gmT, G);
  conv_gemm<512, 1><<<4 * 192, 512, 0, stream>>>(Wr_out, G, b_out, nullptr, out, 0);
}

// Round 5
// 1064.766 us; speedup vs baseline: 1.1405x; 1.1405x over previous
//
#include <hip/hip_runtime.h>
#include <stdint.h>
#include <stddef.h>

typedef __attribute__((ext_vector_type(4))) float floatx4;
typedef __attribute__((ext_vector_type(8))) short shortx8;
typedef __attribute__((ext_vector_type(4))) short shortx4;
typedef __attribute__((ext_vector_type(4))) _Float16 halfx4;

#define DEVI static __device__ __forceinline__

DEVI uint16_t f2bf(float f) {
  uint32_t u = __builtin_bit_cast(uint32_t, f);
  u += 0x7fffu + ((u >> 16) & 1u);
  return (uint16_t)(u >> 16);
}
DEVI float bf2f(uint16_t u) {
  return __builtin_bit_cast(float, (uint32_t)u << 16);
}

// async global->LDS, 16 bytes per lane
DEVI void gload_lds16(const void* g, void* lds) {
  unsigned int off = (unsigned int)(uintptr_t)lds;
  __builtin_amdgcn_global_load_lds(
      (const __attribute__((address_space(1))) unsigned int*)g,
      (__attribute__((address_space(3))) unsigned int*)off,
      16, 0, 0);
}

// ---------------- prep kernels ----------------

// inp [384][512][64] fp32 -> Xb [384*64][512] bf16, LDS-transposed for coalescing.
__global__ __launch_bounds__(256) void k_prep_x(const float* __restrict__ inp,
                                                uint16_t* __restrict__ Xb) {
  __shared__ float T[64 * 65];
  const int tid = threadIdx.x;
  const int t = blockIdx.x >> 3, cb = blockIdx.x & 7;
  const float* src = inp + ((size_t)t * 512 + cb * 64) * 64;
  {
    int ci = tid >> 2, so = (tid & 3) * 16;
#pragma unroll
    for (int j = 0; j < 4; ++j) {
      float4 v = *(const float4*)&src[ci * 64 + so + 4 * j];
      T[ci * 65 + so + 4 * j + 0] = v.x;
      T[ci * 65 + so + 4 * j + 1] = v.y;
      T[ci * 65 + so + 4 * j + 2] = v.z;
      T[ci * 65 + so + 4 * j + 3] = v.w;
    }
  }
  __syncthreads();
  {
    int s = tid >> 2, co = (tid & 3) * 16;
    uint16_t* dst = Xb + ((size_t)(t * 64 + s) * 512) + cb * 64 + co;
    shortx8 o0, o1;
#pragma unroll
    for (int j = 0; j < 8; ++j) o0[j] = (short)f2bf(T[(co + j) * 65 + s]);
#pragma unroll
    for (int j = 0; j < 8; ++j) o1[j] = (short)f2bf(T[(co + 8 + j) * 65 + s]);
    *(shortx8*)dst = o0;
    *(shortx8*)(dst + 8) = o1;
  }
}

// w_in [2560][512][3][3] fp32 -> Wr [9][2560][512] bf16 with co' = e*512+h*64+d
__global__ __launch_bounds__(256) void k_prep_win(const float* __restrict__ w_in,
                                                  const float* __restrict__ b_in,
                                                  uint16_t* __restrict__ Wr,
                                                  float* __restrict__ bias_p) {
  __shared__ float B[4608];
  const int tid = threadIdx.x;
  const int cp = blockIdx.x;
  const int e = cp >> 9, h = (cp >> 6) & 7, d = cp & 63;
  const int co = e * 512 + d * 8 + h;
  const float* src = w_in + (size_t)co * 4608;
#pragma unroll
  for (int it = 0; it < 9; ++it) {
    int i2 = it * 256 + tid;
    *(float2*)&B[i2 * 2] = *(const float2*)&src[i2 * 2];
  }
  if (tid == 0) bias_p[cp] = b_in[co];
  __syncthreads();
  const int ci = tid * 2;
#pragma unroll
  for (int tap = 0; tap < 9; ++tap) {
    uint32_t pk = (uint32_t)f2bf(B[ci * 9 + tap]) |
                  ((uint32_t)f2bf(B[(ci + 1) * 9 + tap]) << 16);
    *(uint32_t*)&Wr[((size_t)tap * 2560 + cp) * 512 + ci] = pk;
  }
}

// w_out [512][512][3][3] fp32 -> Wr [9][512][512] bf16, in-channel perm c2'=h*64+d
__global__ __launch_bounds__(256) void k_prep_wout(const float* __restrict__ w_out,
                                                   uint16_t* __restrict__ Wr) {
  __shared__ float B[4608];
  const int tid = threadIdx.x;
  const int co2 = blockIdx.x;
  const float* src = w_out + (size_t)co2 * 4608;
#pragma unroll
  for (int it = 0; it < 9; ++it) {
    int i2 = it * 256 + tid;
    *(float2*)&B[i2 * 2] = *(const float2*)&src[i2 * 2];
  }
  __syncthreads();
  const int c2 = tid * 2;
  const int oci0 = (c2 & 63) * 8 + (c2 >> 6);
  const int oci1 = ((c2 + 1) & 63) * 8 + ((c2 + 1) >> 6);
#pragma unroll
  for (int tap = 0; tap < 9; ++tap) {
    uint32_t pk = (uint32_t)f2bf(B[oci0 * 9 + tap]) |
                  ((uint32_t)f2bf(B[oci1 * 9 + tap]) << 16);
    *(uint32_t*)&Wr[((size_t)tap * 512 + co2) * 512 + c2] = pk;
  }
}

// masks -> transposed [h][k][q]; amT = am*log2(e) - 8 (offset folds the
// softmax-stability shift; numerator & denominator scale identically).
// gmT as uint8.
__global__ __launch_bounds__(256) void k_prep_mask(const float* __restrict__ am,
                                                   const int* __restrict__ gm,
                                                   float* __restrict__ amT,
                                                   uint8_t* __restrict__ gmT) {
  __shared__ float A_[64 * 65];
  __shared__ float G_[64 * 65];
  const int tid = threadIdx.x;
  const int b = blockIdx.x;
  const int h = b / 36, rr = b % 36;
  const int q0 = (rr / 6) * 64, k0 = (rr % 6) * 64;
  {
    int qr = tid >> 2, ko = (tid & 3) * 16;
    const float* ap = am + ((size_t)h * 384 + q0 + qr) * 384 + k0 + ko;
    const int* gp = gm + ((size_t)h * 384 + q0 + qr) * 384 + k0 + ko;
#pragma unroll
    for (int j = 0; j < 4; ++j) {
      float4 v = *(const float4*)(ap + 4 * j);
      int4 g = *(const int4*)(gp + 4 * j);
      int kk = ko + 4 * j;
      A_[(kk + 0) * 65 + qr] = v.x;
      A_[(kk + 1) * 65 + qr] = v.y;
      A_[(kk + 2) * 65 + qr] = v.z;
      A_[(kk + 3) * 65 + qr] = v.w;
      G_[(kk + 0) * 65 + qr] = (float)g.x;
      G_[(kk + 1) * 65 + qr] = (float)g.y;
      G_[(kk + 2) * 65 + qr] = (float)g.z;
      G_[(kk + 3) * 65 + qr] = (float)g.w;
    }
  }
  __syncthreads();
  {
    const float L2E = 1.44269504f;
    int kr = tid >> 2, qo = (tid & 3) * 16;
    float* aop = amT + ((size_t)h * 384 + k0 + kr) * 384 + q0 + qo;
    uint8_t* gop = gmT + ((size_t)h * 384 + k0 + kr) * 384 + q0 + qo;
    uint32_t gw[4];
#pragma unroll
    for (int j = 0; j < 4; ++j) {
      float4 o;
      o.x = A_[kr * 65 + qo + 4 * j + 0] * L2E - 8.0f;
      o.y = A_[kr * 65 + qo + 4 * j + 1] * L2E - 8.0f;
      o.z = A_[kr * 65 + qo + 4 * j + 2] * L2E - 8.0f;
      o.w = A_[kr * 65 + qo + 4 * j + 3] * L2E - 8.0f;
      *(float4*)(aop + 4 * j) = o;
      gw[j] = (uint32_t)(uint8_t)G_[kr * 65 + qo + 4 * j + 0] |
              ((uint32_t)(uint8_t)G_[kr * 65 + qo + 4 * j + 1] << 8) |
              ((uint32_t)(uint8_t)G_[kr * 65 + qo + 4 * j + 2] << 16) |
              ((uint32_t)(uint8_t)G_[kr * 65 + qo + 4 * j + 3] << 24);
    }
    uint4 gv = {gw[0], gw[1], gw[2], gw[3]};
    *(uint4*)gop = gv;
  }
}

// ---------------- implicit-GEMM 3x3 conv (pad 1) — R2-proven shape ----------------
template <int MTOT, int EPI>
__global__ __launch_bounds__(256) void conv_gemm(const uint16_t* __restrict__ W,
                                                 const uint16_t* __restrict__ X,
                                                 const float* __restrict__ bias,
                                                 uint16_t* __restrict__ Fo,
                                                 float* __restrict__ Oo) {
  __shared__ __attribute__((aligned(16))) uint16_t Wl[128 * 64];
  __shared__ __attribute__((aligned(16))) uint16_t Xl[128 * 64];

  const int tid = threadIdx.x;
  const int lane = tid & 63;
  const int wave = tid >> 6;
  const int quad = lane >> 4;
  const int l15 = lane & 15;
  const int wm = wave >> 1;
  const int wn = wave & 1;

  const int m_blk = blockIdx.x / 192;
  const int n_blk = blockIdx.x % 192;
  const int m0 = m_blk * 128;
  const long n0 = (long)n_blk * 128;

  const int srow = wave * 32 + (lane >> 3);
  const int spos = lane & 7;

  floatx4 acc[4][4];
#pragma unroll
  for (int i = 0; i < 4; ++i)
#pragma unroll
    for (int j = 0; j < 4; ++j) acc[i][j] = (floatx4)0.0f;

  int arow[4];
#pragma unroll
  for (int mt = 0; mt < 4; ++mt) arow[mt] = wm * 64 + mt * 16 + l15;

  for (int kc = 0; kc < 8; ++kc) {
    for (int tap = 0; tap < 9; ++tap) {
      __syncthreads();
      if (tap == 0) {
#pragma unroll
        for (int i = 0; i < 4; ++i) {
          int row = srow + i * 8;
          int c = spos ^ (row & 7);
          gload_lds16(X + ((n0 + row) * 512 + kc * 64 + c * 8),
                      Xl + row * 64 + spos * 8);
        }
      }
      {
        const uint16_t* wg = W + ((size_t)tap * MTOT + m0) * 512 + kc * 64;
#pragma unroll
        for (int i = 0; i < 4; ++i) {
          int row = srow + i * 8;
          int c = spos ^ (row & 7);
          gload_lds16(wg + (size_t)row * 512 + c * 8, Wl + row * 64 + spos * 8);
        }
      }
      __syncthreads();

      const int dy = tap / 3 - 1, dx = tap % 3 - 1;
      int brow[4];
      bool bok[4];
#pragma unroll
      for (int nt = 0; nt < 4; ++nt) {
        int s = nt * 16 + l15;
        int y = (s >> 3) + dy, x = (s & 7) + dx;
        bool ok = ((unsigned)y < 8u) && ((unsigned)x < 8u);
        bok[nt] = ok;
        brow[nt] = wn * 64 + (ok ? (y * 8 + x) : 0);
      }

#pragma unroll
      for (int ks = 0; ks < 2; ++ks) {
        shortx8 af[4], bf[4];
#pragma unroll
        for (int mt = 0; mt < 4; ++mt) {
          int pos = ((ks << 2) | quad) ^ (arow[mt] & 7);
          af[mt] = *(const shortx8*)(Wl + arow[mt] * 64 + pos * 8);
        }
#pragma unroll
        for (int nt = 0; nt < 4; ++nt) {
          int pos = ((ks << 2) | quad) ^ (brow[nt] & 7);
          shortx8 v = *(const shortx8*)(Xl + brow[nt] * 64 + pos * 8);
          bf[nt] = bok[nt] ? v : (shortx8)(short)0;
        }
#pragma unroll
        for (int mt = 0; mt < 4; ++mt)
#pragma unroll
          for (int nt = 0; nt < 4; ++nt)
            acc[mt][nt] = __builtin_amdgcn_mfma_f32_16x16x32_bf16(
                af[mt], bf[nt], acc[mt][nt], 0, 0, 0);
      }
    }
  }

  if (EPI == 0) {
#pragma unroll
    for (int mt = 0; mt < 4; ++mt) {
      int cpb = m0 + wm * 64 + mt * 16 + quad * 4;
      floatx4 bv = *(const floatx4*)(bias + cpb);
      int e = cpb >> 9, h = (cpb >> 6) & 7, d0 = cpb & 63;
#pragma unroll
      for (int nt = 0; nt < 4; ++nt) {
        long ng = n0 + wn * 64 + nt * 16 + l15;
        int t = (int)(ng >> 6), p = (int)(ng & 63);
        shortx4 pk;
#pragma unroll
        for (int r = 0; r < 4; ++r) pk[r] = (short)f2bf(acc[mt][nt][r] + bv[r]);
        *(shortx4*)(Fo + ((((size_t)(e * 8 + h) * 64 + p) * 384 + t) * 64 + d0)) = pk;
      }
    }
  } else {
#pragma unroll
    for (int mt = 0; mt < 4; ++mt) {
      int co = m0 + wm * 64 + mt * 16 + quad * 4;
      floatx4 bv = *(const floatx4*)(bias + co);
#pragma unroll
      for (int nt = 0; nt < 4; ++nt) {
        long ng = n0 + wn * 64 + nt * 16 + l15;
        int t = (int)(ng >> 6), s = (int)(ng & 63);
        float* op = Oo + ((size_t)t * 512 + co) * 64 + s;
#pragma unroll
        for (int r = 0; r < 4; ++r) op[(size_t)r * 64] = acc[mt][nt][r] + bv[r];
      }
    }
  }
}

// ---------------- agent-aware attention, no-max softmax ----------------
// S offset of -8 (folded into amT) keeps exp2 in f16/f32 range; numerator
// and denominator scale identically so softmax is exact. No cross-lane ops
// in the k-loop; l reduced across quads once at the end.
__global__ __launch_bounds__(256) void attn_kernel(const uint16_t* __restrict__ F,
                                                   const float* __restrict__ amT,
                                                   const uint8_t* __restrict__ gmT,
                                                   uint16_t* __restrict__ G) {
  __shared__ __attribute__((aligned(16))) _Float16 Vt[64 * 392];  // [d][kk]

  const int tid = threadIdx.x;
  const int lane = tid & 63;
  const int wave = tid >> 6;
  const int quad = lane >> 4;
  const int l15 = lane & 15;

  const int qt = blockIdx.x % 6;
  const int hp = blockIdx.x / 6;
  const int h = hp >> 6, p = hp & 63;

  const size_t slab = (size_t)384 * 64;
  const uint16_t* Ks = F + ((size_t)(0 * 8 + h) * 64 + p) * slab;
  const uint16_t* Ko = F + ((size_t)(1 * 8 + h) * 64 + p) * slab;
  const uint16_t* Qs = F + ((size_t)(2 * 8 + h) * 64 + p) * slab;
  const uint16_t* Qo = F + ((size_t)(3 * 8 + h) * 64 + p) * slab;
  const uint16_t* Vv = F + ((size_t)(4 * 8 + h) * 64 + p) * slab;

  if (tid < 192) {
    const int kk0 = tid * 2;
    const uint16_t* v0 = Vv + (size_t)kk0 * 64;
#pragma unroll
    for (int dc = 0; dc < 8; ++dc) {
      shortx8 a = *(const shortx8*)(v0 + dc * 8);
      shortx8 b = *(const shortx8*)(v0 + 64 + dc * 8);
#pragma unroll
      for (int e = 0; e < 8; ++e) {
        _Float16 fa = (_Float16)bf2f((uint16_t)a[e]);
        _Float16 fb = (_Float16)bf2f((uint16_t)b[e]);
        uint32_t pk = (uint32_t)__builtin_bit_cast(uint16_t, fa) |
                      ((uint32_t)__builtin_bit_cast(uint16_t, fb) << 16);
        *(uint32_t*)&Vt[(dc * 8 + e) * 392 + kk0] = pk;
      }
    }
  }

  const int q0 = qt * 64 + wave * 16;
  shortx8 qsf[2], qof[2];
#pragma unroll
  for (int ks = 0; ks < 2; ++ks) {
    qsf[ks] = *(const shortx8*)(Qs + (size_t)(q0 + l15) * 64 + ks * 32 + quad * 8);
    qof[ks] = *(const shortx8*)(Qo + (size_t)(q0 + l15) * 64 + ks * 32 + quad * 8);
  }

  floatx4 Os[4], Oo[4];
#pragma unroll
  for (int i = 0; i < 4; ++i) { Os[i] = (floatx4)0.0f; Oo[i] = (floatx4)0.0f; }
  float ls = 0.f, lo = 0.f;  // per-lane partial row-sums

  const float C1 = 0.125f * 1.44269504f;

  __syncthreads();

  for (int kb = 0; kb < 6; ++kb) {
    const int k0 = kb * 64;

    const float* amr = amT + ((size_t)h * 384 + k0 + quad * 4) * 384 + q0 + l15;
    const uint8_t* gmr = gmT + ((size_t)h * 384 + k0 + quad * 4) * 384 + q0 + l15;
    float am[4][4];
    uint8_t gm[4][4];
#pragma unroll
    for (int nt = 0; nt < 4; ++nt)
#pragma unroll
      for (int r = 0; r < 4; ++r) {
        am[nt][r] = amr[((size_t)nt * 16 + r) * 384];
        gm[nt][r] = gmr[((size_t)nt * 16 + r) * 384];
      }

    floatx4 Ss[4], So[4];
#pragma unroll
    for (int nt = 0; nt < 4; ++nt) { Ss[nt] = (floatx4)0.0f; So[nt] = (floatx4)0.0f; }
#pragma unroll
    for (int nt = 0; nt < 4; ++nt) {
      const size_t krow = (size_t)(k0 + nt * 16 + l15) * 64;
#pragma unroll
      for (int ks = 0; ks < 2; ++ks) {
        shortx8 ka = *(const shortx8*)(Ks + krow + ks * 32 + quad * 8);
        Ss[nt] = __builtin_amdgcn_mfma_f32_16x16x32_bf16(ka, qsf[ks], Ss[nt], 0, 0, 0);
        shortx8 kb_ = *(const shortx8*)(Ko + krow + ks * 32 + quad * 8);
        So[nt] = __builtin_amdgcn_mfma_f32_16x16x32_bf16(kb_, qof[ks], So[nt], 0, 0, 0);
      }
    }

    halfx4 pbs[4], pbo[4];
#pragma unroll
    for (int kt = 0; kt < 4; ++kt)
#pragma unroll
      for (int r = 0; r < 4; ++r) {
        float ps = exp2f(Ss[kt][r] * C1 + am[kt][r]);
        float po = exp2f(So[kt][r] * C1 + am[kt][r]);
        ls += ps;
        lo += po;
        bool gb = gm[kt][r] != 0;
        pbs[kt][r] = gb ? (_Float16)ps : (_Float16)0.f;
        pbo[kt][r] = gb ? (_Float16)0.f : (_Float16)po;
      }

#pragma unroll
    for (int dt = 0; dt < 4; ++dt) {
      const _Float16* vrow = Vt + (size_t)(dt * 16 + l15) * 392 + k0;
#pragma unroll
      for (int kt = 0; kt < 4; ++kt) {
        halfx4 va = *(const halfx4*)(vrow + kt * 16 + quad * 4);
        Os[dt] = __builtin_amdgcn_mfma_f32_16x16x16f16(va, pbs[kt], Os[dt], 0, 0, 0);
        Oo[dt] = __builtin_amdgcn_mfma_f32_16x16x16f16(va, pbo[kt], Oo[dt], 0, 0, 0);
      }
    }
  }

  // cross-quad reduction of the row-sums (lanes sharing l15)
  ls += __shfl_xor(ls, 16);
  ls += __shfl_xor(ls, 32);
  lo += __shfl_xor(lo, 16);
  lo += __shfl_xor(lo, 32);

  const float is = 1.f / ls, io = 1.f / lo;
  const int q = q0 + l15;
#pragma unroll
  for (int dt = 0; dt < 4; ++dt) {
    shortx4 pk;
#pragma unroll
    for (int r = 0; r < 4; ++r) pk[r] = (short)f2bf(Os[dt][r] * is + Oo[dt][r] * io);
    *(shortx4*)(G + ((size_t)q * 64 + p) * 512 + h * 64 + dt * 16 + quad * 4) = pk;
  }
}

// ---------------- launch ----------------

extern "C" void kernel_launch(void* const* d_in, const int* in_sizes, int n_in,
                              void* d_out, int out_size, void* d_ws, size_t ws_size,
                              hipStream_t stream) {
  (void)in_sizes; (void)n_in; (void)out_size;

  const float* inp   = (const float*)d_in[0];
  const float* amask = (const float*)d_in[1];
  const int*   gmask = (const int*)d_in[2];
  const float* w_in  = (const float*)d_in[3];
  const float* b_in  = (const float*)d_in[4];
  const float* w_out = (const float*)d_in[5];
  const float* b_out = (const float*)d_in[6];
  float* out = (float*)d_out;

  const size_t SZ_WRIN  = (size_t)9 * 2560 * 512 * 2;
  const size_t SZ_WROUT = (size_t)9 * 512 * 512 * 2;
  const size_t SZ_BIAS  = 2560 * 4;
  const size_t SZ_XB    = (size_t)24576 * 512 * 2;
  const size_t SZ_F     = (size_t)5 * 8 * 64 * 384 * 64 * 2;
  if (ws_size < SZ_WRIN + SZ_WROUT + SZ_BIAS + SZ_XB + SZ_F) return;

  char* ws = (char*)d_ws;
  uint16_t* Wr_in  = (uint16_t*)ws;  ws += SZ_WRIN;
  uint16_t* Wr_out = (uint16_t*)ws;  ws += SZ_WROUT;
  float*    bias_p = (float*)ws;     ws += SZ_BIAS;
  uint16_t* Xb     = (uint16_t*)ws;  ws += SZ_XB;
  uint16_t* F      = (uint16_t*)ws;  ws += SZ_F;
  uint16_t* G      = Xb;             // Xb dead after conv_in
  float*    amT    = (float*)Wr_in;  // Wr_in dead after conv_in
  uint8_t*  gmT    = (uint8_t*)(amT + (size_t)8 * 384 * 384);

  k_prep_x<<<3072, 256, 0, stream>>>(inp, Xb);
  k_prep_win<<<2560, 256, 0, stream>>>(w_in, b_in, Wr_in, bias_p);
  k_prep_wout<<<512, 256, 0, stream>>>(w_out, Wr_out);
  conv_gemm<2560, 0><<<20 * 192, 256, 0, stream>>>(Wr_in, Xb, bias_p, F, nullptr);
  k_prep_mask<<<288, 256, 0, stream>>>(amask, gmask, amT, gmT);
  attn_kernel<<<512 * 6, 256, 0, stream>>>(F, amT, gmT, G);
  conv_gemm<512, 1><<<4 * 192, 256, 0, stream>>>(Wr_out, G, b_out, nullptr, out);
}